// Round 1
// baseline (392.849 us; speedup 1.0000x reference)
//
#include <hip/hip_runtime.h>
#include <math.h>

// Single-query MHA, algebraically collapsed:
//   s[l,h] = x_l . p_h         (p_h = Wk_h^T q_h / sqrt(D); k-bias shift cancels in softmax)
//   z_h    = sum_l softmax(s)_lh * x_l
//   attn_o = Wv z_h + bv ; out = Wo attn + bo
// All fp32. No max-subtraction needed: |s| <= |x_l||p_h| ~ 32 << 88 (fp32 exp range).

#define L_SEQ   32768
#define E_DIM   1024
#define NHEAD   8
#define HDIM    128
#define NBLK_M  256                       // fused-kernel blocks (1 per CU)
#define ROWS_PER_BLK  (L_SEQ / NBLK_M)    // 128
#define WAVES_M 8                         // 512 threads
#define ROWS_PER_WAVE (ROWS_PER_BLK / WAVES_M)  // 16

// ---------------- q = Wq x0 + bq : wave-per-output GEMV ----------------
__global__ __launch_bounds__(256) void proj_q(
    const float* __restrict__ W, const float* __restrict__ bias,
    const float* __restrict__ x, float* __restrict__ q)
{
  const int t = threadIdx.x, wave = t >> 6, lane = t & 63;
  const int o = blockIdx.x * 4 + wave;
  const float4* Wr = (const float4*)(W + (size_t)o * E_DIM);
  const float4* xr = (const float4*)x;   // row 0 of x
  float a = 0.f;
#pragma unroll
  for (int k = 0; k < 4; ++k) {
    float4 wv = Wr[lane + 64 * k];
    float4 xv = xr[lane + 64 * k];
    a += wv.x * xv.x + wv.y * xv.y + wv.z * xv.z + wv.w * xv.w;
  }
#pragma unroll
  for (int m = 1; m < 64; m <<= 1) a += __shfl_xor(a, m, 64);
  if (lane == 0) q[o] = a + bias[o];
}

// ---------------- P_T[h][e] = (1/sqrt(D)) sum_d q[h*128+d] * Wk[h*128+d][e] ----------------
__global__ __launch_bounds__(128) void make_p(
    const float* __restrict__ W, const float* __restrict__ q,
    float* __restrict__ P_T)
{
  const int h = blockIdx.y;
  const int e = blockIdx.x * 128 + threadIdx.x;
  const float* qh = q + h * HDIM;                              // lane-uniform (scalarized)
  const float* Wb = W + ((size_t)E_DIM + (size_t)h * HDIM) * E_DIM + e;  // Wk block rows
  float a = 0.f;
#pragma unroll 8
  for (int d = 0; d < HDIM; ++d) a += qh[d] * Wb[(size_t)d * E_DIM];
  P_T[h * E_DIM + e] = a * 0.08838834764831845f;               // 1/sqrt(128)
}

// ---------------- fused scores + exp + weighted x accumulation (single pass over x) ----------------
__global__ __launch_bounds__(512, 2) void attn_fused(
    const float* __restrict__ x,
    const float* __restrict__ P_T,       // [8][1024]
    float* __restrict__ partial_z,       // [NBLK_M][8][1024]
    float* __restrict__ partial_sumw)    // [NBLK_M][8]
{
  __shared__ float P_lds[NHEAD * E_DIM];   // 32 KB
  __shared__ float z_lds[NHEAD * E_DIM];   // 32 KB  (total exactly 64 KB)

  const int t = threadIdx.x;
  const int wave = t >> 6;
  const int lane = t & 63;
  const int blk = blockIdx.x;

  // stage P into LDS, zero z accumulator (2048 float4 each / 512 threads)
  {
    const float4* src = (const float4*)P_T;
    float4* dst = (float4*)P_lds;
    float4* zd = (float4*)z_lds;
    const float4 zero4 = make_float4(0.f, 0.f, 0.f, 0.f);
#pragma unroll
    for (int i = 0; i < 4; ++i) {
      dst[i * 512 + t] = src[i * 512 + t];
      zd[i * 512 + t] = zero4;
    }
  }
  __syncthreads();

  // per-lane z accumulators: cols {4*lane + 256k + c} x 8 heads = 128 VGPRs
  float acc[128];
#pragma unroll
  for (int i = 0; i < 128; ++i) acc[i] = 0.f;
  float sumw[NHEAD];
#pragma unroll
  for (int h = 0; h < NHEAD; ++h) sumw[h] = 0.f;

  const size_t row0 = (size_t)blk * ROWS_PER_BLK + (size_t)wave * ROWS_PER_WAVE;

  // software-pipelined x row loads
  float4 xv[4];
  {
    const float4* xr = (const float4*)(x + row0 * E_DIM);
#pragma unroll
    for (int k = 0; k < 4; ++k) xv[k] = xr[lane + 64 * k];
  }

  for (int r = 0; r < ROWS_PER_WAVE; ++r) {
    float4 xn[4];
    if (r + 1 < ROWS_PER_WAVE) {
      const float4* xr = (const float4*)(x + (row0 + r + 1) * E_DIM);
#pragma unroll
      for (int k = 0; k < 4; ++k) xn[k] = xr[lane + 64 * k];
    }

    // 8 per-head score partials; P_lds[h][4*lane+256k..+3]: quarter-wave covers all
    // 32 banks twice -> 2-way aliasing = free (m136)
    float s[NHEAD];
#pragma unroll
    for (int h = 0; h < NHEAD; ++h) {
      const float4* pr = (const float4*)(P_lds + h * E_DIM);
      float a = 0.f;
#pragma unroll
      for (int k = 0; k < 4; ++k) {
        float4 p = pr[lane + 64 * k];
        a += xv[k].x * p.x + xv[k].y * p.y + xv[k].z * p.z + xv[k].w * p.w;
      }
      s[h] = a;
    }
    // full-wave butterfly: every lane ends with the complete dot products
#pragma unroll
    for (int m = 1; m < 64; m <<= 1) {
#pragma unroll
      for (int h = 0; h < NHEAD; ++h) s[h] += __shfl_xor(s[h], m, 64);
    }
    float w[NHEAD];
#pragma unroll
    for (int h = 0; h < NHEAD; ++h) {
      w[h] = __expf(s[h]);        // safe: |s| bounded well under fp32 exp range
      sumw[h] += w[h];
    }
#pragma unroll
    for (int h = 0; h < NHEAD; ++h) {
#pragma unroll
      for (int k = 0; k < 4; ++k) {
        acc[h * 16 + k * 4 + 0] += w[h] * xv[k].x;
        acc[h * 16 + k * 4 + 1] += w[h] * xv[k].y;
        acc[h * 16 + k * 4 + 2] += w[h] * xv[k].z;
        acc[h * 16 + k * 4 + 3] += w[h] * xv[k].w;
      }
    }
    if (r + 1 < ROWS_PER_WAVE) {
#pragma unroll
      for (int k = 0; k < 4; ++k) xv[k] = xn[k];
    }
  }

  // combine per-wave register partials into z_lds (waves serialized; all waves
  // cover the same columns so they must not RMW concurrently)
  for (int ww = 0; ww < WAVES_M; ++ww) {
    if (wave == ww) {
#pragma unroll
      for (int h = 0; h < NHEAD; ++h) {
#pragma unroll
        for (int k = 0; k < 4; ++k) {
          float4* zp = (float4*)(z_lds + h * E_DIM) + lane + 64 * k;
          float4 z = *zp;
          z.x += acc[h * 16 + k * 4 + 0];
          z.y += acc[h * 16 + k * 4 + 1];
          z.z += acc[h * 16 + k * 4 + 2];
          z.w += acc[h * 16 + k * 4 + 3];
          *zp = z;
        }
      }
    }
    __syncthreads();
  }

  // sum-of-weights combine (reuse P_lds as staging; all P reads are done)
  float* sw_stage = P_lds;   // [WAVES_M][NHEAD]
  if (lane == 0) {
#pragma unroll
    for (int h = 0; h < NHEAD; ++h) sw_stage[wave * NHEAD + h] = sumw[h];
  }
  __syncthreads();
  if (t < NHEAD) {
    float s = 0.f;
#pragma unroll
    for (int wv = 0; wv < WAVES_M; ++wv) s += sw_stage[wv * NHEAD + t];
    partial_sumw[blk * NHEAD + t] = s;
  }

  // write block partial z (coalesced)
  {
    const float4* zs = (const float4*)z_lds;
    float4* zd = (float4*)(partial_z + (size_t)blk * (NHEAD * E_DIM));
#pragma unroll
    for (int i = 0; i < 4; ++i) zd[i * 512 + t] = zs[i * 512 + t];
  }
}

// ---------------- reduce partials: zn[h][e] = sum_b pz / sum_b psumw ----------------
__global__ __launch_bounds__(256) void reduce_z(
    const float* __restrict__ partial_z,
    const float* __restrict__ partial_sumw,
    float* __restrict__ zn)
{
  __shared__ float red[256];
  __shared__ float swst[4][NHEAD];
  __shared__ float sumw_s[NHEAD];
  const int t = threadIdx.x;
  const int lane = t & 63, wave = t >> 6;

  // total sumw, redundantly per block (cheap: 8 KB)
  float sw[NHEAD];
  {
    const float4* p = (const float4*)(partial_sumw + t * NHEAD);
    float4 a0 = p[0], a1 = p[1];
    sw[0] = a0.x; sw[1] = a0.y; sw[2] = a0.z; sw[3] = a0.w;
    sw[4] = a1.x; sw[5] = a1.y; sw[6] = a1.z; sw[7] = a1.w;
  }
#pragma unroll
  for (int m = 1; m < 64; m <<= 1) {
#pragma unroll
    for (int h = 0; h < NHEAD; ++h) sw[h] += __shfl_xor(sw[h], m, 64);
  }
  if (lane == 0) {
#pragma unroll
    for (int h = 0; h < NHEAD; ++h) swst[wave][h] = sw[h];
  }
  __syncthreads();
  if (t < NHEAD) sumw_s[t] = swst[0][t] + swst[1][t] + swst[2][t] + swst[3][t];

  // 32 outputs per block, 8 partial-groups of 32 blocks each
  const int o = blockIdx.x * 32 + (t & 31);
  const int g = t >> 5;
  float a = 0.f;
  for (int b = g; b < NBLK_M; b += 8) a += partial_z[(size_t)b * (NHEAD * E_DIM) + o];
  red[t] = a;
  __syncthreads();
  if (t < 32) {
    float s2 = 0.f;
#pragma unroll
    for (int gg = 0; gg < 8; ++gg) s2 += red[gg * 32 + t];
    const int oo = blockIdx.x * 32 + t;
    zn[oo] = s2 / sumw_s[oo >> 10];   // oo = h*1024 + e
  }
}

// ---------------- attn[o] = Wv[o] . zn[h(o)] + bv[o] ----------------
__global__ __launch_bounds__(256) void proj_v(
    const float* __restrict__ W, const float* __restrict__ bias,
    const float* __restrict__ zn, float* __restrict__ attn)
{
  const int t = threadIdx.x, wave = t >> 6, lane = t & 63;
  const int o = blockIdx.x * 4 + wave;
  const float4* Wr = (const float4*)(W + ((size_t)2 * E_DIM + o) * E_DIM);
  const float4* zr = (const float4*)(zn + (size_t)(o >> 7) * E_DIM);
  float a = 0.f;
#pragma unroll
  for (int k = 0; k < 4; ++k) {
    float4 wv = Wr[lane + 64 * k];
    float4 zv = zr[lane + 64 * k];
    a += wv.x * zv.x + wv.y * zv.y + wv.z * zv.z + wv.w * zv.w;
  }
#pragma unroll
  for (int m = 1; m < 64; m <<= 1) a += __shfl_xor(a, m, 64);
  if (lane == 0) attn[o] = a + bias[2 * E_DIM + o];
}

// ---------------- out[e] = Wo[e] . attn + bo[e] ----------------
__global__ __launch_bounds__(256) void proj_o(
    const float* __restrict__ Wo, const float* __restrict__ bo,
    const float* __restrict__ attn, float* __restrict__ out)
{
  const int t = threadIdx.x, wave = t >> 6, lane = t & 63;
  const int o = blockIdx.x * 4 + wave;
  const float4* Wr = (const float4*)(Wo + (size_t)o * E_DIM);
  const float4* vr = (const float4*)attn;
  float a = 0.f;
#pragma unroll
  for (int k = 0; k < 4; ++k) {
    float4 wv = Wr[lane + 64 * k];
    float4 vv = vr[lane + 64 * k];
    a += wv.x * vv.x + wv.y * vv.y + wv.z * vv.z + wv.w * vv.w;
  }
#pragma unroll
  for (int m = 1; m < 64; m <<= 1) a += __shfl_xor(a, m, 64);
  if (lane == 0) out[o] = a + bo[o];
}

extern "C" void kernel_launch(void* const* d_in, const int* in_sizes, int n_in,
                              void* d_out, int out_size, void* d_ws, size_t ws_size,
                              hipStream_t stream)
{
  const float* x  = (const float*)d_in[0];   // [32768,1024]
  const float* Wi = (const float*)d_in[1];   // [3072,1024]
  const float* bi = (const float*)d_in[2];   // [3072]
  const float* Wo = (const float*)d_in[3];   // [1024,1024]
  const float* bo = (const float*)d_in[4];   // [1024]
  float* out = (float*)d_out;                // [1024] fp32

  // workspace layout (bytes): total ~8.1 MiB
  char* ws = (char*)d_ws;
  float* q     = (float*)(ws + 0);        // 1024 f  ->  4096
  float* P_T   = (float*)(ws + 4096);     // 8192 f  -> 36864
  float* zn    = (float*)(ws + 36864);    // 8192 f  -> 69632
  float* attn  = (float*)(ws + 69632);    // 1024 f  -> 73728
  float* psumw = (float*)(ws + 73728);    // 2048 f  -> 81920
  float* pz    = (float*)(ws + 81920);    // 256*8192 f -> 8 MiB

  proj_q    <<<256, 256, 0, stream>>>(Wi, bi, x, q);
  make_p    <<<dim3(8, 8), 128, 0, stream>>>(Wi, q, P_T);
  attn_fused<<<NBLK_M, 512, 0, stream>>>(x, P_T, pz, psumw);
  reduce_z  <<<256, 256, 0, stream>>>(pz, psumw, zn);
  proj_v    <<<256, 256, 0, stream>>>(Wi, bi, zn, attn);
  proj_o    <<<256, 256, 0, stream>>>(Wo, bo, attn, out);
}

// Round 2
// 244.291 us; speedup vs baseline: 1.6081x; 1.6081x over previous
//
#include <hip/hip_runtime.h>
#include <math.h>

// Single-query MHA, algebraically collapsed:
//   s[l,h] = x_l . p_h         (p_h = Wk_h^T q_h / sqrt(D); k-bias shift cancels in softmax)
//   z_h    = sum_l softmax(s)_lh * x_l
//   attn   = Wv z + bv ; out = Wo attn + bo
// All fp32. No max-subtraction needed: |s| ~ N(0,1), max ~ 5 << 88 (fp32 exp range).
//
// attn_fused2 is two-phase per 16-row tile to keep per-thread acc at 16 VGPRs
// (round-1 version held 128 -> scratch spill -> 3x FETCH, 7x WRITE, 2.1 TB/s).

#define L_SEQ   32768
#define E_DIM   1024
#define NHEAD   8
#define HDIM    128
#define TILE_R  16
#define WAVES_M 8            // 512 threads

// ---------------- q = Wq x0 + bq : wave-per-output GEMV ----------------
__global__ __launch_bounds__(256) void proj_q(
    const float* __restrict__ W, const float* __restrict__ bias,
    const float* __restrict__ x, float* __restrict__ q)
{
  const int t = threadIdx.x, wave = t >> 6, lane = t & 63;
  const int o = blockIdx.x * 4 + wave;
  const float4* Wr = (const float4*)(W + (size_t)o * E_DIM);
  const float4* xr = (const float4*)x;   // row 0 of x
  float a = 0.f;
#pragma unroll
  for (int k = 0; k < 4; ++k) {
    float4 wv = Wr[lane + 64 * k];
    float4 xv = xr[lane + 64 * k];
    a += wv.x * xv.x + wv.y * xv.y + wv.z * xv.z + wv.w * xv.w;
  }
#pragma unroll
  for (int m = 1; m < 64; m <<= 1) a += __shfl_xor(a, m, 64);
  if (lane == 0) q[o] = a + bias[o];
}

// ---------------- P_T[h][e] = (1/sqrt(D)) sum_d q[h*128+d] * Wk[h*128+d][e] ----------------
__global__ __launch_bounds__(128) void make_p(
    const float* __restrict__ W, const float* __restrict__ q,
    float* __restrict__ P_T)
{
  const int h = blockIdx.y;
  const int e = blockIdx.x * 128 + threadIdx.x;
  const float* qh = q + h * HDIM;                              // lane-uniform (scalarized)
  const float* Wb = W + ((size_t)E_DIM + (size_t)h * HDIM) * E_DIM + e;  // Wk block rows
  float a0 = 0.f, a1 = 0.f, a2 = 0.f, a3 = 0.f;
#pragma unroll 4
  for (int d = 0; d < HDIM; d += 4) {
    a0 += qh[d + 0] * Wb[(size_t)(d + 0) * E_DIM];
    a1 += qh[d + 1] * Wb[(size_t)(d + 1) * E_DIM];
    a2 += qh[d + 2] * Wb[(size_t)(d + 2) * E_DIM];
    a3 += qh[d + 3] * Wb[(size_t)(d + 3) * E_DIM];
  }
  P_T[h * E_DIM + e] = ((a0 + a1) + (a2 + a3)) * 0.08838834764831845f;   // 1/sqrt(128)
}

// ---------------- fused scores + exp + weighted-x accumulation ----------------
// Per block: rows_per_blk rows, processed in 16-row tiles.
// Phase A: wave w scores rows {2w, 2w+1} of the tile (x from HBM, P from LDS).
// Phase B: thread t accumulates cols {2t,2t+1} x 8 heads over the tile's 16 rows
//          (x re-read as float2 -> L2 hit; w from LDS broadcast). 16 acc VGPRs.
__global__ __launch_bounds__(512, 4) void attn_fused2(
    const float* __restrict__ x,
    const float* __restrict__ P_T,       // [8][1024]
    float* __restrict__ partial_z,       // [nblk][8][1024]
    float* __restrict__ partial_sumw,    // [nblk][8]
    int rows_per_blk)
{
  __shared__ __align__(16) float P_lds[NHEAD * E_DIM];        // 32 KB
  __shared__ __align__(16) float w_tile[2][TILE_R][NHEAD];    // 1 KB, double-buffered
  __shared__ __align__(16) float sw_stage[WAVES_M][NHEAD];    // 256 B

  const int t = threadIdx.x;
  const int wave = t >> 6;
  const int lane = t & 63;
  const size_t row0 = (size_t)blockIdx.x * rows_per_blk;
  const int ntiles = rows_per_blk >> 4;

  // stage P into LDS (2048 float4 / 512 threads)
  {
    const float4* src = (const float4*)P_T;
    float4* dst = (float4*)P_lds;
#pragma unroll
    for (int i = 0; i < 4; ++i) dst[i * 512 + t] = src[i * 512 + t];
  }
  __syncthreads();

  float acc[16];
#pragma unroll
  for (int i = 0; i < 16; ++i) acc[i] = 0.f;
  float sumw[NHEAD];
#pragma unroll
  for (int h = 0; h < NHEAD; ++h) sumw[h] = 0.f;

  for (int tile = 0; tile < ntiles; ++tile) {
    const int buf = tile & 1;
    const size_t trow = row0 + (size_t)tile * TILE_R;

    // ---- phase A: score 2 rows per wave (both rows loaded up-front for MLP)
    {
      const int ra = wave * 2, rb = wave * 2 + 1;
      const float4* xra = (const float4*)(x + (trow + ra) * E_DIM);
      const float4* xrb = (const float4*)(x + (trow + rb) * E_DIM);
      float4 xva[4], xvb[4];
#pragma unroll
      for (int k = 0; k < 4; ++k) xva[k] = xra[lane + 64 * k];
#pragma unroll
      for (int k = 0; k < 4; ++k) xvb[k] = xrb[lane + 64 * k];

#pragma unroll
      for (int rr = 0; rr < 2; ++rr) {
        float s[NHEAD];
#pragma unroll
        for (int h = 0; h < NHEAD; ++h) {
          const float4* pr = (const float4*)(P_lds + h * E_DIM);
          float a = 0.f;
#pragma unroll
          for (int k = 0; k < 4; ++k) {
            float4 p = pr[lane + 64 * k];
            float4 xv = rr ? xvb[k] : xva[k];
            a += xv.x * p.x + xv.y * p.y + xv.z * p.z + xv.w * p.w;
          }
          s[h] = a;
        }
#pragma unroll
        for (int m = 1; m < 64; m <<= 1) {
#pragma unroll
          for (int h = 0; h < NHEAD; ++h) s[h] += __shfl_xor(s[h], m, 64);
        }
        float w[NHEAD];
#pragma unroll
        for (int h = 0; h < NHEAD; ++h) { w[h] = __expf(s[h]); sumw[h] += w[h]; }
        if (lane == 0) {
          float4* wd = (float4*)&w_tile[buf][wave * 2 + rr][0];
          wd[0] = make_float4(w[0], w[1], w[2], w[3]);
          wd[1] = make_float4(w[4], w[5], w[6], w[7]);
        }
      }
    }
    __syncthreads();

    // ---- phase B: accumulate tile into acc (cols 2t,2t+1; all 8 heads)
    {
      const float* xb = x + trow * E_DIM + 2 * t;
#pragma unroll
      for (int r4 = 0; r4 < TILE_R; r4 += 4) {
        float2 xv2[4];
#pragma unroll
        for (int j = 0; j < 4; ++j) xv2[j] = *(const float2*)(xb + (size_t)(r4 + j) * E_DIM);
        float4 wlo[4], whi[4];
#pragma unroll
        for (int j = 0; j < 4; ++j) {
          const float4* wp = (const float4*)&w_tile[buf][r4 + j][0];
          wlo[j] = wp[0]; whi[j] = wp[1];
        }
#pragma unroll
        for (int j = 0; j < 4; ++j) {
          acc[0]  += wlo[j].x * xv2[j].x;  acc[1]  += wlo[j].x * xv2[j].y;
          acc[2]  += wlo[j].y * xv2[j].x;  acc[3]  += wlo[j].y * xv2[j].y;
          acc[4]  += wlo[j].z * xv2[j].x;  acc[5]  += wlo[j].z * xv2[j].y;
          acc[6]  += wlo[j].w * xv2[j].x;  acc[7]  += wlo[j].w * xv2[j].y;
          acc[8]  += whi[j].x * xv2[j].x;  acc[9]  += whi[j].x * xv2[j].y;
          acc[10] += whi[j].y * xv2[j].x;  acc[11] += whi[j].y * xv2[j].y;
          acc[12] += whi[j].z * xv2[j].x;  acc[13] += whi[j].z * xv2[j].y;
          acc[14] += whi[j].w * xv2[j].x;  acc[15] += whi[j].w * xv2[j].y;
        }
      }
    }
    // no second barrier: next phase A writes w_tile[1-buf]; the barrier after it
    // protects buf from being overwritten before all B-readers of it are done.
  }

  // write block partial z directly from registers (coalesced per head)
  {
    float* zd = partial_z + (size_t)blockIdx.x * (NHEAD * E_DIM) + 2 * t;
#pragma unroll
    for (int h = 0; h < NHEAD; ++h)
      *(float2*)(zd + h * E_DIM) = make_float2(acc[2 * h], acc[2 * h + 1]);
  }

  // sum-of-weights: stage per-wave, reduce by first 8 threads
  if (lane == 0) {
    float4* sd = (float4*)&sw_stage[wave][0];
    sd[0] = make_float4(sumw[0], sumw[1], sumw[2], sumw[3]);
    sd[1] = make_float4(sumw[4], sumw[5], sumw[6], sumw[7]);
  }
  __syncthreads();
  if (t < NHEAD) {
    float s = 0.f;
#pragma unroll
    for (int wv = 0; wv < WAVES_M; ++wv) s += sw_stage[wv][t];
    partial_sumw[blockIdx.x * NHEAD + t] = s;
  }
}

// ---------------- reduce partials: zn[h][e] = sum_b pz / sum_b psumw ----------------
__global__ __launch_bounds__(256) void reduce_z(
    const float* __restrict__ partial_z,
    const float* __restrict__ partial_sumw,
    float* __restrict__ zn, int nblk)
{
  __shared__ float red[256];
  __shared__ __align__(16) float swst[4][NHEAD];
  __shared__ float sumw_s[NHEAD];
  const int t = threadIdx.x;
  const int lane = t & 63, wave = t >> 6;

  // total sumw, redundantly per block (cheap)
  float sw[NHEAD];
#pragma unroll
  for (int h = 0; h < NHEAD; ++h) sw[h] = 0.f;
  for (int b = t; b < nblk; b += 256) {
    const float4* p = (const float4*)(partial_sumw + (size_t)b * NHEAD);
    float4 a0 = p[0], a1 = p[1];
    sw[0] += a0.x; sw[1] += a0.y; sw[2] += a0.z; sw[3] += a0.w;
    sw[4] += a1.x; sw[5] += a1.y; sw[6] += a1.z; sw[7] += a1.w;
  }
#pragma unroll
  for (int m = 1; m < 64; m <<= 1) {
#pragma unroll
    for (int h = 0; h < NHEAD; ++h) sw[h] += __shfl_xor(sw[h], m, 64);
  }
  if (lane == 0) {
#pragma unroll
    for (int h = 0; h < NHEAD; ++h) swst[wave][h] = sw[h];
  }
  __syncthreads();
  if (t < NHEAD) sumw_s[t] = swst[0][t] + swst[1][t] + swst[2][t] + swst[3][t];

  // 32 outputs per block, 8 partial-groups
  const int o = blockIdx.x * 32 + (t & 31);
  const int g = t >> 5;
  float a = 0.f;
  for (int b = g; b < nblk; b += 8) a += partial_z[(size_t)b * (NHEAD * E_DIM) + o];
  red[t] = a;
  __syncthreads();
  if (t < 32) {
    float s2 = 0.f;
#pragma unroll
    for (int gg = 0; gg < 8; ++gg) s2 += red[gg * 32 + t];
    const int oo = blockIdx.x * 32 + t;
    zn[oo] = s2 / sumw_s[oo >> 10];   // oo = h*1024 + e
  }
}

// ---------------- attn[o] = Wv[o] . zn[h(o)] + bv[o] ----------------
__global__ __launch_bounds__(256) void proj_v(
    const float* __restrict__ W, const float* __restrict__ bias,
    const float* __restrict__ zn, float* __restrict__ attn)
{
  const int t = threadIdx.x, wave = t >> 6, lane = t & 63;
  const int o = blockIdx.x * 4 + wave;
  const float4* Wr = (const float4*)(W + ((size_t)2 * E_DIM + o) * E_DIM);
  const float4* zr = (const float4*)(zn + (size_t)(o >> 7) * E_DIM);
  float a = 0.f;
#pragma unroll
  for (int k = 0; k < 4; ++k) {
    float4 wv = Wr[lane + 64 * k];
    float4 zv = zr[lane + 64 * k];
    a += wv.x * zv.x + wv.y * zv.y + wv.z * zv.z + wv.w * zv.w;
  }
#pragma unroll
  for (int m = 1; m < 64; m <<= 1) a += __shfl_xor(a, m, 64);
  if (lane == 0) attn[o] = a + bias[2 * E_DIM + o];
}

// ---------------- out[e] = Wo[e] . attn + bo[e] ----------------
__global__ __launch_bounds__(256) void proj_o(
    const float* __restrict__ Wo, const float* __restrict__ bo,
    const float* __restrict__ attn, float* __restrict__ out)
{
  const int t = threadIdx.x, wave = t >> 6, lane = t & 63;
  const int o = blockIdx.x * 4 + wave;
  const float4* Wr = (const float4*)(Wo + (size_t)o * E_DIM);
  const float4* vr = (const float4*)attn;
  float a = 0.f;
#pragma unroll
  for (int k = 0; k < 4; ++k) {
    float4 wv = Wr[lane + 64 * k];
    float4 vv = vr[lane + 64 * k];
    a += wv.x * vv.x + wv.y * vv.y + wv.z * vv.z + wv.w * vv.w;
  }
#pragma unroll
  for (int m = 1; m < 64; m <<= 1) a += __shfl_xor(a, m, 64);
  if (lane == 0) out[o] = a + bo[o];
}

extern "C" void kernel_launch(void* const* d_in, const int* in_sizes, int n_in,
                              void* d_out, int out_size, void* d_ws, size_t ws_size,
                              hipStream_t stream)
{
  const float* x  = (const float*)d_in[0];   // [32768,1024]
  const float* Wi = (const float*)d_in[1];   // [3072,1024]
  const float* bi = (const float*)d_in[2];   // [3072]
  const float* Wo = (const float*)d_in[3];   // [1024,1024]
  const float* bo = (const float*)d_in[4];   // [1024]
  float* out = (float*)d_out;                // [1024] fp32

  // pick partial-block count from available workspace (constant across calls)
  const size_t hdr = 90112;
  int nblk = 128;
  if (ws_size >= hdr + (size_t)512 * NHEAD * E_DIM * 4) nblk = 512;
  else if (ws_size >= hdr + (size_t)256 * NHEAD * E_DIM * 4) nblk = 256;
  const int rows_per_blk = L_SEQ / nblk;

  // workspace layout (bytes)
  char* ws = (char*)d_ws;
  float* q     = (float*)(ws + 0);        // 1024 f
  float* P_T   = (float*)(ws + 4096);     // 8192 f
  float* zn    = (float*)(ws + 36864);    // 8192 f
  float* attn  = (float*)(ws + 69632);    // 1024 f
  float* psumw = (float*)(ws + 73728);    // nblk*8 f  (max 16 KB)
  float* pz    = (float*)(ws + hdr);      // nblk*8192 f

  proj_q     <<<256, 256, 0, stream>>>(Wi, bi, x, q);
  make_p     <<<dim3(8, 8), 128, 0, stream>>>(Wi, q, P_T);
  attn_fused2<<<nblk, 512, 0, stream>>>(x, P_T, pz, psumw, rows_per_blk);
  reduce_z   <<<256, 256, 0, stream>>>(pz, psumw, zn, nblk);
  proj_v     <<<256, 256, 0, stream>>>(Wi, bi, zn, attn);
  proj_o     <<<256, 256, 0, stream>>>(Wo, bo, attn, out);
}

// Round 3
// 243.119 us; speedup vs baseline: 1.6159x; 1.0048x over previous
//
#include <hip/hip_runtime.h>
#include <math.h>

// Single-query MHA, algebraically collapsed:
//   s[l,h] = x_l . p_h         (p_h = Wk_h^T q_h / sqrt(D); k-bias shift cancels in softmax)
//   z_h    = sum_l softmax(s)_lh * x_l
//   attn   = Wv z + bv ; out = Wo attn + bo
// All fp32. No max-subtraction needed: |s| ~ N(0,1), max ~ 5 << 88 (fp32 exp range).
//
// attn_fused3: two-phase per 16-row tile (16 acc VGPRs/thread, no spill) with a
// transpose-reduce for the 16 dot-products per wave (17 shfl per 2 rows instead
// of 48/row) -- round-2 version was LDS-pipe-bound on butterfly shuffles.

#define L_SEQ   32768
#define E_DIM   1024
#define NHEAD   8
#define HDIM    128
#define TILE_R  16
#define WAVES_M 8            // 512 threads

// ---------------- q = Wq x0 + bq : wave-per-output GEMV ----------------
__global__ __launch_bounds__(256) void proj_q(
    const float* __restrict__ W, const float* __restrict__ bias,
    const float* __restrict__ x, float* __restrict__ q)
{
  const int t = threadIdx.x, wave = t >> 6, lane = t & 63;
  const int o = blockIdx.x * 4 + wave;
  const float4* Wr = (const float4*)(W + (size_t)o * E_DIM);
  const float4* xr = (const float4*)x;   // row 0 of x
  float a = 0.f;
#pragma unroll
  for (int k = 0; k < 4; ++k) {
    float4 wv = Wr[lane + 64 * k];
    float4 xv = xr[lane + 64 * k];
    a += wv.x * xv.x + wv.y * xv.y + wv.z * xv.z + wv.w * xv.w;
  }
#pragma unroll
  for (int m = 1; m < 64; m <<= 1) a += __shfl_xor(a, m, 64);
  if (lane == 0) q[o] = a + bias[o];
}

// ---------------- P_T[h][e] = (1/sqrt(D)) sum_d q[h*128+d] * Wk[h*128+d][e] ----------------
__global__ __launch_bounds__(128) void make_p(
    const float* __restrict__ W, const float* __restrict__ q,
    float* __restrict__ P_T)
{
  const int h = blockIdx.y;
  const int e = blockIdx.x * 128 + threadIdx.x;
  const float* qh = q + h * HDIM;                              // lane-uniform (scalarized)
  const float* Wb = W + ((size_t)E_DIM + (size_t)h * HDIM) * E_DIM + e;  // Wk block rows
  float a0 = 0.f, a1 = 0.f, a2 = 0.f, a3 = 0.f;
#pragma unroll 4
  for (int d = 0; d < HDIM; d += 4) {
    a0 += qh[d + 0] * Wb[(size_t)(d + 0) * E_DIM];
    a1 += qh[d + 1] * Wb[(size_t)(d + 1) * E_DIM];
    a2 += qh[d + 2] * Wb[(size_t)(d + 2) * E_DIM];
    a3 += qh[d + 3] * Wb[(size_t)(d + 3) * E_DIM];
  }
  P_T[h * E_DIM + e] = ((a0 + a1) + (a2 + a3)) * 0.08838834764831845f;   // 1/sqrt(128)
}

// ---------------- fused scores + exp + weighted-x accumulation ----------------
// Phase A: wave w scores rows {2w, 2w+1} of the 16-row tile; the 16 partial dots
//   (2 rows x 8 heads) are reduced with a transpose-butterfly so each lane ends
//   holding ONE fully-reduced score (17 shfl total), takes 1 exp, and lanes<16
//   write w_tile with one ds_write_b32.
// Phase B: thread t accumulates cols {2t,2t+1} x 8 heads over the tile's 16 rows
//   (x re-read as float2 -> L2 hit; w from LDS broadcast). 16 acc VGPRs.
__global__ __launch_bounds__(512, 4) void attn_fused3(
    const float* __restrict__ x,
    const float* __restrict__ P_T,       // [8][1024]
    float* __restrict__ partial_z,       // [nblk][8][1024]
    float* __restrict__ partial_sumw,    // [nblk][8]
    int rows_per_blk)
{
  __shared__ __align__(16) float P_lds[NHEAD * E_DIM];        // 32 KB
  __shared__ __align__(16) float w_tile[2][TILE_R][NHEAD];    // 1 KB, double-buffered
  __shared__ __align__(16) float sw_stage[WAVES_M][NHEAD];    // 256 B

  const int t = threadIdx.x;
  const int wave = t >> 6;
  const int lane = t & 63;
  const size_t row0 = (size_t)blockIdx.x * rows_per_blk;
  const int ntiles = rows_per_blk >> 4;

  // transpose-reduce final index mapping: lane ends with value j = b0*8 + b1*4 + b2*2 + b3
  // where bk = bit k of lane; value j = rr*8 + h.
  const int rr_l = lane & 1;
  const int h_l = (((lane >> 1) & 1) << 2) | (((lane >> 2) & 1) << 1) | ((lane >> 3) & 1);

  // stage P into LDS (2048 float4 / 512 threads)
  {
    const float4* src = (const float4*)P_T;
    float4* dst = (float4*)P_lds;
#pragma unroll
    for (int i = 0; i < 4; ++i) dst[i * 512 + t] = src[i * 512 + t];
  }
  __syncthreads();

  float acc[16];
#pragma unroll
  for (int i = 0; i < 16; ++i) acc[i] = 0.f;
  float sumw_own = 0.f;    // this lane's (rr_l, h_l) running sum of weights

  for (int tile = 0; tile < ntiles; ++tile) {
    const int buf = tile & 1;
    const size_t trow = row0 + (size_t)tile * TILE_R;

    // ---- phase A: score 2 rows per wave
    {
      const float4* xra = (const float4*)(x + (trow + wave * 2 + 0) * E_DIM);
      const float4* xrb = (const float4*)(x + (trow + wave * 2 + 1) * E_DIM);
      float4 xva[4], xvb[4];
#pragma unroll
      for (int k = 0; k < 4; ++k) xva[k] = xra[lane + 64 * k];
#pragma unroll
      for (int k = 0; k < 4; ++k) xvb[k] = xrb[lane + 64 * k];

      float v[16];   // v[h] = row-a partial, v[8+h] = row-b partial
#pragma unroll
      for (int h = 0; h < NHEAD; ++h) {
        const float4* pr = (const float4*)(P_lds + h * E_DIM);
        float a0 = 0.f, a1 = 0.f;
#pragma unroll
        for (int k = 0; k < 4; ++k) {
          float4 p = pr[lane + 64 * k];    // one LDS read feeds both rows
          a0 += xva[k].x * p.x + xva[k].y * p.y + xva[k].z * p.z + xva[k].w * p.w;
          a1 += xvb[k].x * p.x + xvb[k].y * p.y + xvb[k].z * p.z + xvb[k].w * p.w;
        }
        v[h] = a0; v[8 + h] = a1;
      }

      // transpose-butterfly: 4 splitting levels (16->1 values), then 2 plain levels
#pragma unroll
      for (int lev = 0; lev < 4; ++lev) {
        const int d = 1 << lev;
        const int half = 8 >> lev;
#pragma unroll
        for (int i = 0; i < half; ++i) {
          float lo = v[i], hi = v[i + half];
          float keep = (lane & d) ? hi : lo;
          float oth  = (lane & d) ? lo : hi;
          v[i] = keep + __shfl_xor(oth, d, 64);
        }
      }
      float tot = v[0];
      tot += __shfl_xor(tot, 16, 64);
      tot += __shfl_xor(tot, 32, 64);

      const float w = __expf(tot);
      sumw_own += w;                        // replicated in lanes>=16; only lanes<16 used
      if (lane < 16) w_tile[buf][wave * 2 + rr_l][h_l] = w;
    }
    __syncthreads();

    // ---- phase B: accumulate tile into acc (cols 2t,2t+1; all 8 heads)
    {
      const float* xb = x + trow * E_DIM + 2 * t;
#pragma unroll
      for (int r4 = 0; r4 < TILE_R; r4 += 4) {
        float2 xv2[4];
#pragma unroll
        for (int j = 0; j < 4; ++j) xv2[j] = *(const float2*)(xb + (size_t)(r4 + j) * E_DIM);
        float4 wlo[4], whi[4];
#pragma unroll
        for (int j = 0; j < 4; ++j) {
          const float4* wp = (const float4*)&w_tile[buf][r4 + j][0];
          wlo[j] = wp[0]; whi[j] = wp[1];
        }
#pragma unroll
        for (int j = 0; j < 4; ++j) {
          acc[0]  += wlo[j].x * xv2[j].x;  acc[1]  += wlo[j].x * xv2[j].y;
          acc[2]  += wlo[j].y * xv2[j].x;  acc[3]  += wlo[j].y * xv2[j].y;
          acc[4]  += wlo[j].z * xv2[j].x;  acc[5]  += wlo[j].z * xv2[j].y;
          acc[6]  += wlo[j].w * xv2[j].x;  acc[7]  += wlo[j].w * xv2[j].y;
          acc[8]  += whi[j].x * xv2[j].x;  acc[9]  += whi[j].x * xv2[j].y;
          acc[10] += whi[j].y * xv2[j].x;  acc[11] += whi[j].y * xv2[j].y;
          acc[12] += whi[j].z * xv2[j].x;  acc[13] += whi[j].z * xv2[j].y;
          acc[14] += whi[j].w * xv2[j].x;  acc[15] += whi[j].w * xv2[j].y;
        }
      }
    }
    // no second barrier: next phase A writes w_tile[1-buf]; the barrier after it
    // protects buf from being overwritten before all B-readers of it are done.
  }

  // write block partial z directly from registers (coalesced per head)
  {
    float* zd = partial_z + (size_t)blockIdx.x * (NHEAD * E_DIM) + 2 * t;
#pragma unroll
    for (int h = 0; h < NHEAD; ++h)
      *(float2*)(zd + h * E_DIM) = make_float2(acc[2 * h], acc[2 * h + 1]);
  }

  // sum-of-weights: combine rr pairs, stage per-wave, reduce by first 8 threads
  {
    float s2 = sumw_own + __shfl_xor(sumw_own, 1, 64);   // both rows of this (wave, head)
    if (lane < 16 && (lane & 1) == 0) sw_stage[wave][h_l] = s2;
  }
  __syncthreads();
  if (t < NHEAD) {
    float s = 0.f;
#pragma unroll
    for (int wv = 0; wv < WAVES_M; ++wv) s += sw_stage[wv][t];
    partial_sumw[blockIdx.x * NHEAD + t] = s;
  }
}

// ---------------- reduce partials: zn[h][e] = sum_b pz / sum_b psumw ----------------
__global__ __launch_bounds__(256) void reduce_z(
    const float* __restrict__ partial_z,
    const float* __restrict__ partial_sumw,
    float* __restrict__ zn, int nblk)
{
  __shared__ float red[256];
  __shared__ __align__(16) float swst[4][NHEAD];
  __shared__ float sumw_s[NHEAD];
  const int t = threadIdx.x;
  const int lane = t & 63, wave = t >> 6;

  // total sumw, redundantly per block (cheap)
  float sw[NHEAD];
#pragma unroll
  for (int h = 0; h < NHEAD; ++h) sw[h] = 0.f;
  for (int b = t; b < nblk; b += 256) {
    const float4* p = (const float4*)(partial_sumw + (size_t)b * NHEAD);
    float4 a0 = p[0], a1 = p[1];
    sw[0] += a0.x; sw[1] += a0.y; sw[2] += a0.z; sw[3] += a0.w;
    sw[4] += a1.x; sw[5] += a1.y; sw[6] += a1.z; sw[7] += a1.w;
  }
#pragma unroll
  for (int m = 1; m < 64; m <<= 1) {
#pragma unroll
    for (int h = 0; h < NHEAD; ++h) sw[h] += __shfl_xor(sw[h], m, 64);
  }
  if (lane == 0) {
#pragma unroll
    for (int h = 0; h < NHEAD; ++h) swst[wave][h] = sw[h];
  }
  __syncthreads();
  if (t < NHEAD) sumw_s[t] = swst[0][t] + swst[1][t] + swst[2][t] + swst[3][t];

  // 32 outputs per block, 8 partial-groups
  const int o = blockIdx.x * 32 + (t & 31);
  const int g = t >> 5;
  float a = 0.f;
  for (int b = g; b < nblk; b += 8) a += partial_z[(size_t)b * (NHEAD * E_DIM) + o];
  red[t] = a;
  __syncthreads();
  if (t < 32) {
    float s2 = 0.f;
#pragma unroll
    for (int gg = 0; gg < 8; ++gg) s2 += red[gg * 32 + t];
    const int oo = blockIdx.x * 32 + t;
    zn[oo] = s2 / sumw_s[oo >> 10];   // oo = h*1024 + e
  }
}

// ---------------- attn[o] = Wv[o] . zn[h(o)] + bv[o] ----------------
__global__ __launch_bounds__(256) void proj_v(
    const float* __restrict__ W, const float* __restrict__ bias,
    const float* __restrict__ zn, float* __restrict__ attn)
{
  const int t = threadIdx.x, wave = t >> 6, lane = t & 63;
  const int o = blockIdx.x * 4 + wave;
  const float4* Wr = (const float4*)(W + ((size_t)2 * E_DIM + o) * E_DIM);
  const float4* zr = (const float4*)(zn + (size_t)(o >> 7) * E_DIM);
  float a = 0.f;
#pragma unroll
  for (int k = 0; k < 4; ++k) {
    float4 wv = Wr[lane + 64 * k];
    float4 zv = zr[lane + 64 * k];
    a += wv.x * zv.x + wv.y * zv.y + wv.z * zv.z + wv.w * zv.w;
  }
#pragma unroll
  for (int m = 1; m < 64; m <<= 1) a += __shfl_xor(a, m, 64);
  if (lane == 0) attn[o] = a + bias[2 * E_DIM + o];
}

// ---------------- out[e] = Wo[e] . attn + bo[e] ----------------
__global__ __launch_bounds__(256) void proj_o(
    const float* __restrict__ Wo, const float* __restrict__ bo,
    const float* __restrict__ attn, float* __restrict__ out)
{
  const int t = threadIdx.x, wave = t >> 6, lane = t & 63;
  const int o = blockIdx.x * 4 + wave;
  const float4* Wr = (const float4*)(Wo + (size_t)o * E_DIM);
  const float4* vr = (const float4*)attn;
  float a = 0.f;
#pragma unroll
  for (int k = 0; k < 4; ++k) {
    float4 wv = Wr[lane + 64 * k];
    float4 vv = vr[lane + 64 * k];
    a += wv.x * vv.x + wv.y * vv.y + wv.z * vv.z + wv.w * vv.w;
  }
#pragma unroll
  for (int m = 1; m < 64; m <<= 1) a += __shfl_xor(a, m, 64);
  if (lane == 0) out[o] = a + bo[o];
}

extern "C" void kernel_launch(void* const* d_in, const int* in_sizes, int n_in,
                              void* d_out, int out_size, void* d_ws, size_t ws_size,
                              hipStream_t stream)
{
  const float* x  = (const float*)d_in[0];   // [32768,1024]
  const float* Wi = (const float*)d_in[1];   // [3072,1024]
  const float* bi = (const float*)d_in[2];   // [3072]
  const float* Wo = (const float*)d_in[3];   // [1024,1024]
  const float* bo = (const float*)d_in[4];   // [1024]
  float* out = (float*)d_out;                // [1024] fp32

  // pick partial-block count from available workspace (constant across calls)
  const size_t hdr = 90112;
  int nblk = 128;
  if (ws_size >= hdr + (size_t)512 * NHEAD * E_DIM * 4) nblk = 512;
  else if (ws_size >= hdr + (size_t)256 * NHEAD * E_DIM * 4) nblk = 256;
  const int rows_per_blk = L_SEQ / nblk;

  // workspace layout (bytes)
  char* ws = (char*)d_ws;
  float* q     = (float*)(ws + 0);        // 1024 f
  float* P_T   = (float*)(ws + 4096);     // 8192 f
  float* zn    = (float*)(ws + 36864);    // 8192 f
  float* attn  = (float*)(ws + 69632);    // 1024 f
  float* psumw = (float*)(ws + 73728);    // nblk*8 f  (max 16 KB)
  float* pz    = (float*)(ws + hdr);      // nblk*8192 f

  proj_q     <<<256, 256, 0, stream>>>(Wi, bi, x, q);
  make_p     <<<dim3(8, 8), 128, 0, stream>>>(Wi, q, P_T);
  attn_fused3<<<nblk, 512, 0, stream>>>(x, P_T, pz, psumw, rows_per_blk);
  reduce_z   <<<256, 256, 0, stream>>>(pz, psumw, zn, nblk);
  proj_v     <<<256, 256, 0, stream>>>(Wi, bi, zn, attn);
  proj_o     <<<256, 256, 0, stream>>>(Wo, bo, attn, out);
}